// Round 3
// baseline (361.172 us; speedup 1.0000x reference)
//
#include <hip/hip_runtime.h>

#define NB 64

struct GradLUT { float k0, v0, ginv, v1; };

__device__ __forceinline__ float4 shade(
    float x, float g,
    const float (*s_knots)[NB] /* unused-shape trick avoided */,
    const float* sk, const float (*sv)[4],
    float gk0, float gv0, float gv1, float ginv)
{
    // Uniform-spacing guess, then exact correction against real knots.
    // idx = largest j in [0,62] with knots[j] <= x (0 if none).
    float fid = fminf(fmaxf(x * (float)(NB - 1), 0.0f), (float)(NB - 2));
    int idx = (int)fid;
    float klo = sk[idx];
    float khi = sk[idx + 1];
    while (idx > 0 && x < klo)        { --idx; khi = klo; klo = sk[idx]; }
    while (idx < NB - 2 && x >= khi)  { ++idx; klo = khi; khi = sk[idx + 1]; }

    float t = (x - klo) / (khi - klo);
    t = fminf(fmaxf(t, 0.0f), 1.0f);
    const float omt = 1.0f - t;

    const float4 v0 = *(const float4*)sv[idx];
    const float4 v1 = *(const float4*)sv[idx + 1];

    // Same algebraic form as reference: v0*(1-t) + v1*t
    float r = v0.x * omt + v1.x * t;
    float gg = v0.y * omt + v1.y * t;
    float b = v0.z * omt + v1.z * t;
    float a = v0.w * omt + v1.w * t;

    // gradient modulation: 2-knot lerp, clamped
    float tg = (g - gk0) * ginv;
    tg = fminf(fmaxf(tg, 0.0f), 1.0f);
    const float mod = gv0 * (1.0f - tg) + gv1 * tg;

    return make_float4(r, gg, b, a * mod);
}

__global__ __launch_bounds__(256) void vr_kernel(
    const float* __restrict__ in,   // [N,2] (x, g) interleaved
    const float* __restrict__ tf,   // [64,5] (knot, r, g, b, a)
    const float* __restrict__ gt,   // [2,2]  (knot, val) x 2
    float* __restrict__ out,        // [N,4]
    int n_pts)
{
    __shared__ float s_knots[NB];
    __shared__ float s_vals[NB][4];   // 16B rows -> ds_read_b128

    for (int i = threadIdx.x; i < NB; i += blockDim.x) {
        s_knots[i]   = tf[i * 5 + 0];
        s_vals[i][0] = tf[i * 5 + 1];
        s_vals[i][1] = tf[i * 5 + 2];
        s_vals[i][2] = tf[i * 5 + 3];
        s_vals[i][3] = tf[i * 5 + 4];
    }
    const float gk0 = gt[0], gv0 = gt[1], gk1 = gt[2], gv1 = gt[3];
    const float ginv = 1.0f / (gk1 - gk0);
    __syncthreads();

    const float2* __restrict__ in2  = (const float2*)in;
    float4* __restrict__       out4 = (float4*)out;

    const int stride = gridDim.x * blockDim.x;
    const int tid0   = blockIdx.x * blockDim.x + threadIdx.x;

    // 2 points per iteration at coalesced offsets i and i+stride:
    // two independent dependence chains -> LDS gather latency overlaps.
    int i = tid0;
    for (; i + stride < n_pts; i += 2 * stride) {
        float2 pa = in2[i];
        float2 pb = in2[i + stride];
        float4 oa = shade(pa.x, pa.y, nullptr, s_knots, s_vals, gk0, gv0, gv1, ginv);
        float4 ob = shade(pb.x, pb.y, nullptr, s_knots, s_vals, gk0, gv0, gv1, ginv);
        out4[i] = oa;
        out4[i + stride] = ob;
    }
    if (i < n_pts) {
        float2 pa = in2[i];
        out4[i] = shade(pa.x, pa.y, nullptr, s_knots, s_vals, gk0, gv0, gv1, ginv);
    }
}

extern "C" void kernel_launch(void* const* d_in, const int* in_sizes, int n_in,
                              void* d_out, int out_size, void* d_ws, size_t ws_size,
                              hipStream_t stream) {
    const float* in = (const float*)d_in[0];   // input_x [N,2]
    const float* tf = (const float*)d_in[1];   // tf_table [64,5]
    const float* gt = (const float*)d_in[2];   // grad_table [2,2]
    float* out = (float*)d_out;

    const int n_pts = in_sizes[0] / 2;         // 16777216

    const int block = 256;
    const int grid  = 2048;                    // 8 blocks/CU; 16 unrolled iters/thread
    vr_kernel<<<grid, block, 0, stream>>>(in, tf, gt, out, n_pts);
}

// Round 6
// 349.524 us; speedup vs baseline: 1.0333x; 1.0333x over previous
//
#include <hip/hip_runtime.h>

#define NB 64

// Native clang vector types: __builtin_nontemporal_load/store require
// pointers to real vector types, not HIP_vector_type structs.
typedef float vfloat2 __attribute__((ext_vector_type(2)));
typedef float vfloat4 __attribute__((ext_vector_type(4)));

__global__ __launch_bounds__(256) void vr_kernel(
    const float* __restrict__ in,   // [N,2] (x, g) interleaved
    const float* __restrict__ tf,   // [64,5] (knot, r, g, b, a)
    const float* __restrict__ gt,   // [2,2]  (knot, val) x 2
    float* __restrict__ out,        // [N,4]
    int n_pts)
{
    __shared__ float s_knots[NB];
    __shared__ float s_vals[NB][4];   // 16B rows; random-idx ds_read_b128 is
                                      // bank-uniform (depth 8 = stride-1 floor)

    for (int i = threadIdx.x; i < NB; i += blockDim.x) {
        s_knots[i]   = tf[i * 5 + 0];
        s_vals[i][0] = tf[i * 5 + 1];
        s_vals[i][1] = tf[i * 5 + 2];
        s_vals[i][2] = tf[i * 5 + 3];
        s_vals[i][3] = tf[i * 5 + 4];
    }
    const float gk0 = gt[0], gv0 = gt[1], gk1 = gt[2], gv1 = gt[3];
    const float ginv = 1.0f / (gk1 - gk0);
    __syncthreads();

    const vfloat2* __restrict__ in2  = (const vfloat2*)in;
    vfloat4* __restrict__       out4 = (vfloat4*)out;

    const int stride = gridDim.x * blockDim.x;
    for (int i = blockIdx.x * blockDim.x + threadIdx.x; i < n_pts; i += stride) {
        // Read-once stream: non-temporal load — skip L2 allocate.
        vfloat2 p = __builtin_nontemporal_load(&in2[i]);
        const float x = p.x;
        const float g = p.y;

        // Uniform-spacing guess, then exact correction against real knots.
        // idx = largest j in [0,62] with knots[j] <= x (0 if none).
        float fid = fminf(fmaxf(x * (float)(NB - 1), 0.0f), (float)(NB - 2));
        int idx = (int)fid;
        float klo = s_knots[idx];
        float khi = s_knots[idx + 1];
        while (idx > 0 && x < klo)       { --idx; khi = klo; klo = s_knots[idx]; }
        while (idx < NB - 2 && x >= khi) { ++idx; klo = khi; khi = s_knots[idx + 1]; }

        float t = (x - klo) / (khi - klo);
        t = fminf(fmaxf(t, 0.0f), 1.0f);
        const float omt = 1.0f - t;

        const vfloat4 v0 = *(const vfloat4*)s_vals[idx];
        const vfloat4 v1 = *(const vfloat4*)s_vals[idx + 1];

        // Same algebraic form as reference: v0*(1-t) + v1*t
        vfloat4 o;
        o.x = v0.x * omt + v1.x * t;
        o.y = v0.y * omt + v1.y * t;
        o.z = v0.z * omt + v1.z * t;

        // gradient modulation: 2-knot lerp, clamped
        float tg = (g - gk0) * ginv;
        tg = fminf(fmaxf(tg, 0.0f), 1.0f);
        const float mod = gv0 * (1.0f - tg) + gv1 * tg;

        o.w = (v0.w * omt + v1.w * t) * mod;

        // Write-once stream: non-temporal store.
        __builtin_nontemporal_store(o, &out4[i]);
    }
}

extern "C" void kernel_launch(void* const* d_in, const int* in_sizes, int n_in,
                              void* d_out, int out_size, void* d_ws, size_t ws_size,
                              hipStream_t stream) {
    const float* in = (const float*)d_in[0];   // input_x [N,2]
    const float* tf = (const float*)d_in[1];   // tf_table [64,5]
    const float* gt = (const float*)d_in[2];   // grad_table [2,2]
    float* out = (float*)d_out;

    const int n_pts = in_sizes[0] / 2;         // 16777216

    const int block = 256;
    const int grid  = 2048;                    // 8 blocks/CU, 32 iters/thread
    vr_kernel<<<grid, block, 0, stream>>>(in, tf, gt, out, n_pts);
}